// Round 1
// baseline (603.565 us; speedup 1.0000x reference)
//
#include <hip/hip_runtime.h>
#include <math.h>

#define HIDC 64
#define HD 256  // H*HID channels

// ---------------- CSR build ----------------
__global__ void count_kernel(const int* __restrict__ ei, int E, int N,
                             int* __restrict__ counts) {
  int e = blockIdx.x * blockDim.x + threadIdx.x;
  int etot = E + N;
  if (e >= etot) return;
  int dst = (e < E) ? ei[E + e] : (e - E);
  atomicAdd(&counts[dst], 1);
}

__global__ __launch_bounds__(1024) void scan_kernel(const int* __restrict__ counts,
                                                    int* __restrict__ row_start, int n) {
  __shared__ int wsum[16];
  __shared__ int carry;
  int tid = threadIdx.x;
  int lane = tid & 63, wid = tid >> 6;
  if (tid == 0) { carry = 0; row_start[0] = 0; }
  __syncthreads();
  for (int base = 0; base < n; base += 1024) {
    int i = base + tid;
    int x = (i < n) ? counts[i] : 0;
#pragma unroll
    for (int offd = 1; offd < 64; offd <<= 1) {
      int t = __shfl_up(x, offd, 64);
      if (lane >= offd) x += t;
    }
    if (lane == 63) wsum[wid] = x;
    __syncthreads();
    if (wid == 0) {
      int s2 = (lane < 16) ? wsum[lane] : 0;
#pragma unroll
      for (int offd = 1; offd < 16; offd <<= 1) {
        int t = __shfl_up(s2, offd, 64);
        if (lane >= offd) s2 += t;
      }
      if (lane < 16) wsum[lane] = s2;
    }
    __syncthreads();
    int pre = (wid > 0 ? wsum[wid - 1] : 0) + carry;
    if (i < n) row_start[i + 1] = pre + x;
    __syncthreads();
    if (tid == 0) carry += wsum[15];
    __syncthreads();
  }
}

__global__ void scatter_kernel(const int* __restrict__ ei, int E, int N,
                               const int* __restrict__ row_start,
                               int* __restrict__ cursor, int* __restrict__ csr_src) {
  int e = blockIdx.x * blockDim.x + threadIdx.x;
  int etot = E + N;
  if (e >= etot) return;
  int src, dst;
  if (e < E) { src = ei[e]; dst = ei[E + e]; } else { src = e - E; dst = src; }
  int pos = row_start[dst] + atomicAdd(&cursor[dst], 1);
  csr_src[pos] = src;
}

// ---------------- GEMM: C[M,256] = A[M,K] @ W[256,K]^T + b ----------------
template <int K>
__global__ __launch_bounds__(256) void gemm_kernel(const float* __restrict__ A,
                                                   const float* __restrict__ W,
                                                   const float* __restrict__ bvec,
                                                   float* __restrict__ C, int M) {
  __shared__ float As[16][68];
  __shared__ float Bs[16][68];
  int tid = threadIdx.x;
  int tx = tid & 15, ty = tid >> 4;
  int m0 = blockIdx.x * 64, n0 = blockIdx.y * 64;
  int lr = tid >> 2, lq = (tid & 3) * 4;
  float acc[4][4] = {};
  for (int k0 = 0; k0 < K; k0 += 16) {
    float4 a4 = make_float4(0.f, 0.f, 0.f, 0.f);
    if (m0 + lr < M) a4 = *(const float4*)&A[(size_t)(m0 + lr) * K + k0 + lq];
    float4 b4 = *(const float4*)&W[(size_t)(n0 + lr) * K + k0 + lq];
    __syncthreads();
    As[lq + 0][lr] = a4.x; As[lq + 1][lr] = a4.y; As[lq + 2][lr] = a4.z; As[lq + 3][lr] = a4.w;
    Bs[lq + 0][lr] = b4.x; Bs[lq + 1][lr] = b4.y; Bs[lq + 2][lr] = b4.z; Bs[lq + 3][lr] = b4.w;
    __syncthreads();
#pragma unroll
    for (int k = 0; k < 16; ++k) {
      float4 av = *(const float4*)&As[k][4 * ty];
      float4 bv = *(const float4*)&Bs[k][4 * tx];
      float aa[4] = {av.x, av.y, av.z, av.w};
      float bb[4] = {bv.x, bv.y, bv.z, bv.w};
#pragma unroll
      for (int i = 0; i < 4; ++i)
#pragma unroll
        for (int j = 0; j < 4; ++j) acc[i][j] += aa[i] * bb[j];
    }
  }
  float4 bias4 = *(const float4*)&bvec[n0 + 4 * tx];
  float bb[4] = {bias4.x, bias4.y, bias4.z, bias4.w};
#pragma unroll
  for (int i = 0; i < 4; ++i) {
    int m = m0 + 4 * ty + i;
    if (m < M) {
      float4 st = make_float4(acc[i][0] + bb[0], acc[i][1] + bb[1],
                              acc[i][2] + bb[2], acc[i][3] + bb[3]);
      *(float4*)&C[(size_t)m * HD + n0 + 4 * tx] = st;
    }
  }
}

// ---------------- Fused GATv2 per-node aggregate + LN + ELU (+ MLP) ----------------
// One wave (64 lanes) per node. Lane l owns channels 4l..4l+3 of the 256 (H*HID).
template <bool LAST>
__global__ __launch_bounds__(256) void gat_kernel(
    const float* __restrict__ xl, const float* __restrict__ xr,
    const float* __restrict__ att, const float* __restrict__ bias,
    const float* __restrict__ gamma, const float* __restrict__ beta,
    const int* __restrict__ row_start, const int* __restrict__ csr_src,
    const float* __restrict__ Wh1, const float* __restrict__ bh1,
    const float* __restrict__ Wh2, const float* __restrict__ bh2,
    float* __restrict__ outp, int N) {
  __shared__ float sh[4][96];
  int wid = threadIdx.x >> 6;
  int lane = threadIdx.x & 63;
  int v = blockIdx.x * 4 + wid;
  if (v >= N) return;
  int c0 = 4 * lane;
  int cc = 4 * (lane & 15);
  float4 xr4 = *(const float4*)&xr[(size_t)v * HD + c0];
  float4 at4 = *(const float4*)&att[c0];
  float acc0 = 0.f, acc1 = 0.f, acc2 = 0.f, acc3 = 0.f;
  float ssum = 0.f;
  int rs = row_start[v], re = row_start[v + 1];
  for (int idx = rs; idx < re; ++idx) {
    int s = csr_src[idx];
    float4 xl4 = *(const float4*)&xl[(size_t)s * HD + c0];
    float t0 = xl4.x + xr4.x, t1 = xl4.y + xr4.y;
    float t2 = xl4.z + xr4.z, t3 = xl4.w + xr4.w;
    float l0 = t0 > 0.f ? t0 : 0.2f * t0;
    float l1 = t1 > 0.f ? t1 : 0.2f * t1;
    float l2 = t2 > 0.f ? t2 : 0.2f * t2;
    float l3 = t3 > 0.f ? t3 : 0.2f * t3;
    float part = l0 * at4.x + l1 * at4.y + l2 * at4.z + l3 * at4.w;
    part += __shfl_xor(part, 1);
    part += __shfl_xor(part, 2);
    part += __shfl_xor(part, 4);
    part += __shfl_xor(part, 8);
    float p = __expf(part);  // softmax shift-invariance: scores are O(1), no max needed
    ssum += p;
    acc0 += p * xl4.x; acc1 += p * xl4.y; acc2 += p * xl4.z; acc3 += p * xl4.w;
  }
  float inv = 1.f / ssum;  // self-loop guarantees ssum > 0
  float hv[4] = {acc0 * inv, acc1 * inv, acc2 * inv, acc3 * inv};
  // sum across the 4 heads (lanes l, l^16, l^32, l^48 share cc)
#pragma unroll
  for (int j = 0; j < 4; ++j) {
    hv[j] += __shfl_xor(hv[j], 16);
    hv[j] += __shfl_xor(hv[j], 32);
  }
  float4 bias4 = *(const float4*)&bias[cc];
  hv[0] = 0.25f * hv[0] + bias4.x;
  hv[1] = 0.25f * hv[1] + bias4.y;
  hv[2] = 0.25f * hv[2] + bias4.z;
  hv[3] = 0.25f * hv[3] + bias4.w;
  // LayerNorm over 64 channels (distinct values live in the 16-lane group)
  float psum = hv[0] + hv[1] + hv[2] + hv[3];
  float psq = hv[0] * hv[0] + hv[1] * hv[1] + hv[2] * hv[2] + hv[3] * hv[3];
#pragma unroll
  for (int o = 1; o < 16; o <<= 1) {
    psum += __shfl_xor(psum, o);
    psq += __shfl_xor(psq, o);
  }
  float mean = psum * (1.f / 64.f);
  float var = psq * (1.f / 64.f) - mean * mean;
  float rstd = rsqrtf(var + 1e-5f);
  float4 g4 = *(const float4*)&gamma[cc];
  float4 be4 = *(const float4*)&beta[cc];
  float y[4];
  y[0] = (hv[0] - mean) * rstd * g4.x + be4.x;
  y[1] = (hv[1] - mean) * rstd * g4.y + be4.y;
  y[2] = (hv[2] - mean) * rstd * g4.z + be4.z;
  y[3] = (hv[3] - mean) * rstd * g4.w + be4.w;
#pragma unroll
  for (int j = 0; j < 4; ++j) y[j] = y[j] > 0.f ? y[j] : expm1f(y[j]);
  if (!LAST) {
    if (lane < 16)
      *(float4*)&outp[(size_t)v * HIDC + cc] =
          make_float4(y[0], y[1], y[2], y[3]);
  } else {
    // fused MLP head: relu(y @ Wh1^T + bh1) @ Wh2^T + bh2 -> out[v][2]
    if (lane < 16) {
      sh[wid][cc + 0] = y[0]; sh[wid][cc + 1] = y[1];
      sh[wid][cc + 2] = y[2]; sh[wid][cc + 3] = y[3];
    }
    // same-wave LDS ops are in-order; no barrier needed (waves independent)
    if (lane < 32) {
      float a = bh1[lane];
      const float* wrow = &Wh1[lane * 64];
#pragma unroll 8
      for (int k = 0; k < 64; ++k) a += sh[wid][k] * wrow[k];
      sh[wid][64 + lane] = fmaxf(a, 0.f);
    }
    if (lane < 2) {
      float o = bh2[lane];
      const float* wrow = &Wh2[lane * 32];
#pragma unroll 8
      for (int k = 0; k < 32; ++k) o += sh[wid][64 + k] * wrow[k];
      outp[(size_t)v * 2 + lane] = o;
    }
  }
}

// ---------------- launch ----------------
extern "C" void kernel_launch(void* const* d_in, const int* in_sizes, int n_in,
                              void* d_out, int out_size, void* d_ws, size_t ws_size,
                              hipStream_t stream) {
  const float* x = (const float*)d_in[0];
  const int* ei = (const int*)d_in[1];
  const float* Wl1 = (const float*)d_in[2]; const float* bl1 = (const float*)d_in[3];
  const float* Wr1 = (const float*)d_in[4]; const float* br1 = (const float*)d_in[5];
  const float* att1 = (const float*)d_in[6]; const float* bias1 = (const float*)d_in[7];
  const float* Wl2 = (const float*)d_in[8]; const float* bl2 = (const float*)d_in[9];
  const float* Wr2 = (const float*)d_in[10]; const float* br2 = (const float*)d_in[11];
  const float* att2 = (const float*)d_in[12]; const float* bias2 = (const float*)d_in[13];
  const float* g1 = (const float*)d_in[14]; const float* be1 = (const float*)d_in[15];
  const float* g2 = (const float*)d_in[16]; const float* be2 = (const float*)d_in[17];
  const float* Wh1 = (const float*)d_in[18]; const float* bh1 = (const float*)d_in[19];
  const float* Wh2 = (const float*)d_in[20]; const float* bh2 = (const float*)d_in[21];
  float* out = (float*)d_out;

  int N = in_sizes[0] / 128;
  int E = in_sizes[1] / 2;
  int ET = E + N;

  char* ws = (char*)d_ws;
  size_t off = 0;
  auto alloc = [&](size_t bytes) {
    void* p = ws + off;
    off += (bytes + 255) & ~(size_t)255;
    return p;
  };
  float* xl = (float*)alloc((size_t)N * HD * 4);
  float* xr = (float*)alloc((size_t)N * HD * 4);
  float* h1 = (float*)alloc((size_t)N * HIDC * 4);
  int* row_start = (int*)alloc((size_t)(N + 1) * 4);
  int* counts = (int*)alloc((size_t)N * 4);
  int* cursor = (int*)alloc((size_t)N * 4);
  int* csr = (int*)alloc((size_t)ET * 4);

  hipMemsetAsync(counts, 0, (size_t)N * 4, stream);
  hipMemsetAsync(cursor, 0, (size_t)N * 4, stream);

  int eb = (ET + 255) / 256;
  count_kernel<<<eb, 256, 0, stream>>>(ei, E, N, counts);
  scan_kernel<<<1, 1024, 0, stream>>>(counts, row_start, N);
  scatter_kernel<<<eb, 256, 0, stream>>>(ei, E, N, row_start, cursor, csr);

  dim3 gg((N + 63) / 64, 4);
  gemm_kernel<128><<<gg, 256, 0, stream>>>(x, Wl1, bl1, xl, N);
  gemm_kernel<128><<<gg, 256, 0, stream>>>(x, Wr1, br1, xr, N);

  int gb = (N + 3) / 4;
  gat_kernel<false><<<gb, 256, 0, stream>>>(xl, xr, att1, bias1, g1, be1,
                                            row_start, csr, nullptr, nullptr,
                                            nullptr, nullptr, h1, N);

  gemm_kernel<64><<<gg, 256, 0, stream>>>(h1, Wl2, bl2, xl, N);
  gemm_kernel<64><<<gg, 256, 0, stream>>>(h1, Wr2, br2, xr, N);

  gat_kernel<true><<<gb, 256, 0, stream>>>(xl, xr, att2, bias2, g2, be2,
                                           row_start, csr, Wh1, bh1, Wh2, bh2,
                                           out, N);
}

// Round 2
// 409.953 us; speedup vs baseline: 1.4723x; 1.4723x over previous
//
#include <hip/hip_runtime.h>
#include <math.h>

#define HIDC 64
#define HD 512  // combined xl|xr channels per node (bf16)

typedef unsigned int uint32;
typedef unsigned short ushort16;
using short8 = __attribute__((ext_vector_type(8))) short;
using f32x4 = __attribute__((ext_vector_type(4))) float;

__device__ inline float ubits(uint32 u) { return __builtin_bit_cast(float, u); }
__device__ inline unsigned short f2bf(float x) {
  uint32 u = __builtin_bit_cast(uint32, x);
  return (unsigned short)((u + 0x7fffu + ((u >> 16) & 1u)) >> 16);
}

template <int CTRL>
__device__ inline float dpp_add(float x) {
  int xi = __builtin_bit_cast(int, x);
  int s = __builtin_amdgcn_update_dpp(0, xi, CTRL, 0xf, 0xf, false);
  return x + __builtin_bit_cast(float, s);
}

// ---------------- CSR build ----------------
__global__ void count_kernel(const int* __restrict__ ei, int E, int N,
                             int* __restrict__ counts) {
  int e = blockIdx.x * blockDim.x + threadIdx.x;
  int etot = E + N;
  if (e >= etot) return;
  int dst = (e < E) ? ei[E + e] : (e - E);
  atomicAdd(&counts[dst], 1);
}

__global__ __launch_bounds__(1024) void scan_kernel(const int* __restrict__ counts,
                                                    int* __restrict__ row_start, int n) {
  __shared__ int wsum[16];
  __shared__ int carry;
  int tid = threadIdx.x;
  int lane = tid & 63, wid = tid >> 6;
  if (tid == 0) { carry = 0; row_start[0] = 0; }
  __syncthreads();
  for (int base = 0; base < n; base += 1024) {
    int i = base + tid;
    int x = (i < n) ? counts[i] : 0;
#pragma unroll
    for (int offd = 1; offd < 64; offd <<= 1) {
      int t = __shfl_up(x, offd, 64);
      if (lane >= offd) x += t;
    }
    if (lane == 63) wsum[wid] = x;
    __syncthreads();
    if (wid == 0) {
      int s2 = (lane < 16) ? wsum[lane] : 0;
#pragma unroll
      for (int offd = 1; offd < 16; offd <<= 1) {
        int t = __shfl_up(s2, offd, 64);
        if (lane >= offd) s2 += t;
      }
      if (lane < 16) wsum[lane] = s2;
    }
    __syncthreads();
    int pre = (wid > 0 ? wsum[wid - 1] : 0) + carry;
    if (i < n) row_start[i + 1] = pre + x;
    __syncthreads();
    if (tid == 0) carry += wsum[15];
    __syncthreads();
  }
}

__global__ void scatter_kernel(const int* __restrict__ ei, int E, int N,
                               const int* __restrict__ row_start,
                               int* __restrict__ cursor, int* __restrict__ csr_src) {
  int e = blockIdx.x * blockDim.x + threadIdx.x;
  int etot = E + N;
  if (e >= etot) return;
  int src, dst;
  if (e < E) { src = ei[e]; dst = ei[E + e]; } else { src = e - E; dst = src; }
  int pos = row_start[dst] + atomicAdd(&cursor[dst], 1);
  csr_src[pos] = src;
}

// ---------------- fp32 -> bf16 pack (vectorized x4) ----------------
__global__ void pack4_kernel(const float* __restrict__ in,
                             unsigned short* __restrict__ out, int n4) {
  int i = blockIdx.x * blockDim.x + threadIdx.x;
  if (i >= n4) return;
  float4 v = ((const float4*)in)[i];
  ushort4 o;
  o.x = f2bf(v.x); o.y = f2bf(v.y); o.z = f2bf(v.z); o.w = f2bf(v.w);
  ((ushort4*)out)[i] = o;
}

// ---------------- MFMA GEMM: C[M,512](bf16) = A[M,K](bf16) @ W[512,K](bf16)^T + bias
// block = 4 waves, each wave a 64(M)x64(N) tile; B-frags in registers, A direct from global.
#define MFMA16 __builtin_amdgcn_mfma_f32_16x16x32_bf16
template <int K>
__global__ __launch_bounds__(256, 2) void mfma_gemm(
    const unsigned short* __restrict__ A, const unsigned short* __restrict__ W,
    const float* __restrict__ bl, const float* __restrict__ br,
    unsigned short* __restrict__ C, int M) {
  int lane = threadIdx.x & 63;
  int wv = threadIdx.x >> 6;
  int m0 = blockIdx.x * 256 + wv * 64;
  int n0 = blockIdx.y * 64;
  int lr = lane & 15, lk = (lane >> 4) * 8;
  const float* bp = (n0 < 256) ? bl : br;
  int nb = n0 & 255;

  short8 bfrag[4][K / 32];
#pragma unroll
  for (int nf = 0; nf < 4; ++nf)
#pragma unroll
    for (int ks = 0; ks < K / 32; ++ks)
      bfrag[nf][ks] = *(const short8*)&W[(size_t)(n0 + nf * 16 + lr) * K + ks * 32 + lk];

  f32x4 acc[4][4];
#pragma unroll
  for (int i = 0; i < 4; ++i)
#pragma unroll
    for (int j = 0; j < 4; ++j) acc[i][j] = (f32x4){0.f, 0.f, 0.f, 0.f};

#pragma unroll
  for (int mf = 0; mf < 4; ++mf) {
    int mr = m0 + mf * 16 + lr;
    int mrc = mr < M ? mr : 0;  // clamp; garbage lands in rows >= M, masked at store
    short8 afrag[K / 32];
#pragma unroll
    for (int ks = 0; ks < K / 32; ++ks)
      afrag[ks] = *(const short8*)&A[(size_t)mrc * K + ks * 32 + lk];
#pragma unroll
    for (int ks = 0; ks < K / 32; ++ks)
#pragma unroll
      for (int nf = 0; nf < 4; ++nf)
        acc[mf][nf] = MFMA16(afrag[ks], bfrag[nf][ks], acc[mf][nf], 0, 0, 0);
  }

  int cr = (lane >> 4) * 4;
#pragma unroll
  for (int mf = 0; mf < 4; ++mf) {
#pragma unroll
    for (int r = 0; r < 4; ++r) {
      int m = m0 + mf * 16 + cr + r;
      if (m < M) {
#pragma unroll
        for (int nf = 0; nf < 4; ++nf) {
          int n = n0 + nf * 16 + lr;
          float v = acc[mf][nf][r] + bp[nb + nf * 16 + lr];
          C[(size_t)m * HD + n] = f2bf(v);
        }
      }
    }
  }
}

// ---------------- Fused GATv2 per-node aggregate + LN + ELU (+ MLP) ----------------
// One wave per node; lane l owns channels 4l..4l+3 of the 256 (H*HID).
// xlr: [N][512] bf16, cols 0-255 = xl, 256-511 = xr.
template <bool LAST>
__global__ __launch_bounds__(256) void gat_kernel(
    const unsigned short* __restrict__ xlr,
    const float* __restrict__ att, const float* __restrict__ bias,
    const float* __restrict__ gamma, const float* __restrict__ beta,
    const int* __restrict__ row_start, const int* __restrict__ csr_src,
    const float* __restrict__ Wh1, const float* __restrict__ bh1,
    const float* __restrict__ Wh2, const float* __restrict__ bh2,
    void* __restrict__ outp, int N) {
  __shared__ float sh[4][96];
  int wid = threadIdx.x >> 6;
  int lane = threadIdx.x & 63;
  int v = blockIdx.x * 4 + wid;
  if (v >= N) return;
  int c0 = 4 * lane;
  int cc = 4 * (lane & 15);

  uint2 ur = *(const uint2*)&xlr[(size_t)v * HD + 256 + c0];
  float xr0 = ubits(ur.x << 16), xr1 = ubits(ur.x & 0xffff0000u);
  float xr2 = ubits(ur.y << 16), xr3 = ubits(ur.y & 0xffff0000u);
  float4 at4 = *(const float4*)&att[c0];

  float acc0 = 0.f, acc1 = 0.f, acc2 = 0.f, acc3 = 0.f;
  float ssum = 0.f;

  auto edge = [&](uint2 u) {
    float x0 = ubits(u.x << 16), x1 = ubits(u.x & 0xffff0000u);
    float x2 = ubits(u.y << 16), x3 = ubits(u.y & 0xffff0000u);
    float t0 = x0 + xr0, t1 = x1 + xr1, t2 = x2 + xr2, t3 = x3 + xr3;
    float l0 = fmaxf(t0, 0.2f * t0);
    float l1 = fmaxf(t1, 0.2f * t1);
    float l2 = fmaxf(t2, 0.2f * t2);
    float l3 = fmaxf(t3, 0.2f * t3);
    float part = l0 * at4.x;
    part = fmaf(l1, at4.y, part);
    part = fmaf(l2, at4.z, part);
    part = fmaf(l3, at4.w, part);
    part = dpp_add<0x121>(part);  // row_ror:1
    part = dpp_add<0x122>(part);  // row_ror:2
    part = dpp_add<0x124>(part);  // row_ror:4
    part = dpp_add<0x128>(part);  // row_ror:8 -> full 16-lane (head) sum
    float p = __expf(part);  // softmax shift-invariance: scores are O(1)
    ssum += p;
    acc0 = fmaf(p, x0, acc0);
    acc1 = fmaf(p, x1, acc1);
    acc2 = fmaf(p, x2, acc2);
    acc3 = fmaf(p, x3, acc3);
  };

  int rs = row_start[v], re = row_start[v + 1];
  int idx = rs;
  for (; idx + 2 <= re; idx += 2) {
    int s0 = csr_src[idx], s1 = csr_src[idx + 1];
    uint2 u0 = *(const uint2*)&xlr[(size_t)s0 * HD + c0];
    uint2 u1 = *(const uint2*)&xlr[(size_t)s1 * HD + c0];
    edge(u0);
    edge(u1);
  }
  if (idx < re) {
    int s0 = csr_src[idx];
    uint2 u0 = *(const uint2*)&xlr[(size_t)s0 * HD + c0];
    edge(u0);
  }

  float inv = 1.f / ssum;  // self-loop guarantees ssum > 0
  float hv[4] = {acc0 * inv, acc1 * inv, acc2 * inv, acc3 * inv};
#pragma unroll
  for (int j = 0; j < 4; ++j) {  // sum across the 4 heads
    hv[j] += __shfl_xor(hv[j], 16);
    hv[j] += __shfl_xor(hv[j], 32);
  }
  float4 bias4 = *(const float4*)&bias[cc];
  hv[0] = 0.25f * hv[0] + bias4.x;
  hv[1] = 0.25f * hv[1] + bias4.y;
  hv[2] = 0.25f * hv[2] + bias4.z;
  hv[3] = 0.25f * hv[3] + bias4.w;
  float psum = hv[0] + hv[1] + hv[2] + hv[3];
  float psq = hv[0] * hv[0] + hv[1] * hv[1] + hv[2] * hv[2] + hv[3] * hv[3];
#pragma unroll
  for (int o = 1; o < 16; o <<= 1) {
    psum += __shfl_xor(psum, o);
    psq += __shfl_xor(psq, o);
  }
  float mean = psum * (1.f / 64.f);
  float var = psq * (1.f / 64.f) - mean * mean;
  float rstd = rsqrtf(var + 1e-5f);
  float4 g4 = *(const float4*)&gamma[cc];
  float4 be4 = *(const float4*)&beta[cc];
  float y[4];
  y[0] = (hv[0] - mean) * rstd * g4.x + be4.x;
  y[1] = (hv[1] - mean) * rstd * g4.y + be4.y;
  y[2] = (hv[2] - mean) * rstd * g4.z + be4.z;
  y[3] = (hv[3] - mean) * rstd * g4.w + be4.w;
#pragma unroll
  for (int j = 0; j < 4; ++j) y[j] = y[j] > 0.f ? y[j] : expm1f(y[j]);

  if (!LAST) {
    if (lane < 16) {
      ushort4 o;
      o.x = f2bf(y[0]); o.y = f2bf(y[1]); o.z = f2bf(y[2]); o.w = f2bf(y[3]);
      *(ushort4*)&((unsigned short*)outp)[(size_t)v * HIDC + cc] = o;
    }
  } else {
    float* out = (float*)outp;
    if (lane < 16) {
      sh[wid][cc + 0] = y[0]; sh[wid][cc + 1] = y[1];
      sh[wid][cc + 2] = y[2]; sh[wid][cc + 3] = y[3];
    }
    if (lane < 32) {  // same-wave LDS ops in order; waves independent
      float a = bh1[lane];
      const float* wrow = &Wh1[lane * 64];
#pragma unroll 8
      for (int k = 0; k < 64; ++k) a += sh[wid][k] * wrow[k];
      sh[wid][64 + lane] = fmaxf(a, 0.f);
    }
    if (lane < 2) {
      float o = bh2[lane];
      const float* wrow = &Wh2[lane * 32];
#pragma unroll 8
      for (int k = 0; k < 32; ++k) o += sh[wid][64 + k] * wrow[k];
      out[(size_t)v * 2 + lane] = o;
    }
  }
}

// ---------------- launch ----------------
extern "C" void kernel_launch(void* const* d_in, const int* in_sizes, int n_in,
                              void* d_out, int out_size, void* d_ws, size_t ws_size,
                              hipStream_t stream) {
  const float* x = (const float*)d_in[0];
  const int* ei = (const int*)d_in[1];
  const float* Wl1 = (const float*)d_in[2]; const float* bl1 = (const float*)d_in[3];
  const float* Wr1 = (const float*)d_in[4]; const float* br1 = (const float*)d_in[5];
  const float* att1 = (const float*)d_in[6]; const float* bias1 = (const float*)d_in[7];
  const float* Wl2 = (const float*)d_in[8]; const float* bl2 = (const float*)d_in[9];
  const float* Wr2 = (const float*)d_in[10]; const float* br2 = (const float*)d_in[11];
  const float* att2 = (const float*)d_in[12]; const float* bias2 = (const float*)d_in[13];
  const float* g1 = (const float*)d_in[14]; const float* be1 = (const float*)d_in[15];
  const float* g2 = (const float*)d_in[16]; const float* be2 = (const float*)d_in[17];
  const float* Wh1 = (const float*)d_in[18]; const float* bh1 = (const float*)d_in[19];
  const float* Wh2 = (const float*)d_in[20]; const float* bh2 = (const float*)d_in[21];
  float* out = (float*)d_out;

  int N = in_sizes[0] / 128;
  int E = in_sizes[1] / 2;
  int ET = E + N;

  char* ws = (char*)d_ws;
  size_t off = 0;
  auto alloc = [&](size_t bytes) {
    void* p = ws + off;
    off += (bytes + 255) & ~(size_t)255;
    return p;
  };
  unsigned short* xlr = (unsigned short*)alloc((size_t)N * HD * 2);   // 51.2 MB
  unsigned short* xb  = (unsigned short*)alloc((size_t)N * 128 * 2);  // 12.8 MB
  unsigned short* h1b = (unsigned short*)alloc((size_t)N * HIDC * 2); // 6.4 MB
  unsigned short* Wc1 = (unsigned short*)alloc((size_t)512 * 128 * 2);
  unsigned short* Wc2 = (unsigned short*)alloc((size_t)512 * 64 * 2);
  int* row_start = (int*)alloc((size_t)(N + 1) * 4);
  int* counts = (int*)alloc((size_t)N * 4);
  int* cursor = (int*)alloc((size_t)N * 4);
  int* csr = (int*)alloc((size_t)ET * 4);

  hipMemsetAsync(counts, 0, (size_t)N * 4, stream);
  hipMemsetAsync(cursor, 0, (size_t)N * 4, stream);

  int eb = (ET + 255) / 256;
  count_kernel<<<eb, 256, 0, stream>>>(ei, E, N, counts);
  scan_kernel<<<1, 1024, 0, stream>>>(counts, row_start, N);
  scatter_kernel<<<eb, 256, 0, stream>>>(ei, E, N, row_start, cursor, csr);

  // packs (fp32 -> bf16, RTNE)
  int nx4 = N * 128 / 4;
  pack4_kernel<<<(nx4 + 255) / 256, 256, 0, stream>>>(x, xb, nx4);
  pack4_kernel<<<(256 * 128 / 4 + 255) / 256, 256, 0, stream>>>(Wl1, Wc1, 256 * 128 / 4);
  pack4_kernel<<<(256 * 128 / 4 + 255) / 256, 256, 0, stream>>>(Wr1, Wc1 + 256 * 128, 256 * 128 / 4);
  pack4_kernel<<<(256 * 64 / 4 + 255) / 256, 256, 0, stream>>>(Wl2, Wc2, 256 * 64 / 4);
  pack4_kernel<<<(256 * 64 / 4 + 255) / 256, 256, 0, stream>>>(Wr2, Wc2 + 256 * 64, 256 * 64 / 4);

  dim3 gg((N + 255) / 256, 8);
  mfma_gemm<128><<<gg, 256, 0, stream>>>(xb, Wc1, bl1, br1, xlr, N);

  int gb = (N + 3) / 4;
  gat_kernel<false><<<gb, 256, 0, stream>>>(xlr, att1, bias1, g1, be1,
                                            row_start, csr, nullptr, nullptr,
                                            nullptr, nullptr, h1b, N);

  mfma_gemm<64><<<gg, 256, 0, stream>>>(h1b, Wc2, bl2, br2, xlr, N);

  gat_kernel<true><<<gb, 256, 0, stream>>>(xlr, att2, bias2, g2, be2,
                                           row_start, csr, Wh1, bh1, Wh2, bh2,
                                           out, N);
}